// Round 1
// baseline (1470.434 us; speedup 1.0000x reference)
//
#include <hip/hip_runtime.h>

// ---- problem constants ----
#define NE 16
#define DD 2048
#define HH 1408
#define HSH 2816
#define TOPK 6
#define TT 4096

typedef __bf16 bf16x8 __attribute__((ext_vector_type(8)));
typedef __bf16 bf16x4 __attribute__((ext_vector_type(4)));
typedef float f32x4 __attribute__((ext_vector_type(4)));

typedef const __attribute__((address_space(1))) void gvoid_t;
typedef __attribute__((address_space(3))) void lvoid_t;

__device__ __forceinline__ void gll16(const void* g, void* l) {
  __builtin_amdgcn_global_load_lds((gvoid_t*)g, (lvoid_t*)l, 16, 0, 0);
}

// ---------------- fp32 -> bf16 convert ----------------
__global__ void k_cvt(const float* __restrict__ s, __bf16* __restrict__ d, long n4) {
  long i = (long)blockIdx.x * blockDim.x + threadIdx.x;
  long stride = (long)gridDim.x * blockDim.x;
  for (; i < n4; i += stride) {
    float4 v = ((const float4*)s)[i];
    bf16x4 o = { (__bf16)v.x, (__bf16)v.y, (__bf16)v.z, (__bf16)v.w };
    ((bf16x4*)d)[i] = o;
  }
}

// ---------------- gate: softmax + biased top-6 ----------------
__global__ __launch_bounds__(256) void k_gate(
    const float* __restrict__ x, const float* __restrict__ gw,
    const float* __restrict__ gb, float* __restrict__ cw,
    int* __restrict__ counts, int* __restrict__ lists) {
  int t = blockIdx.x;
  int lane = threadIdx.x & 63, wave = threadIdx.x >> 6;
  __shared__ float sc[NE];
  const float* xt = x + (size_t)t * DD;
  for (int ei = 0; ei < 4; ++ei) {
    int e = wave * 4 + ei;
    const float* ge = gw + (size_t)e * DD;
    float s = 0.f;
    for (int j = 0; j < DD / 64; ++j) s += xt[lane + 64 * j] * ge[lane + 64 * j];
    for (int o = 32; o; o >>= 1) s += __shfl_xor(s, o);
    if (lane == 0) sc[e] = s;
  }
  __syncthreads();
  if (threadIdx.x == 0) {
    float p[NE], b[NE];
    float m = -1e30f;
    for (int e = 0; e < NE; ++e) m = fmaxf(m, sc[e]);
    float sum = 0.f;
    for (int e = 0; e < NE; ++e) { p[e] = expf(sc[e] - m); sum += p[e]; }
    float inv = 1.f / sum;
    for (int e = 0; e < NE; ++e) { p[e] *= inv; b[e] = p[e] + gb[e]; }
    float out[NE];
    bool used[NE];
    for (int e = 0; e < NE; ++e) { out[e] = 0.f; used[e] = false; }
    for (int k = 0; k < TOPK; ++k) {
      int best = -1; float bv = -1e30f;
      for (int e = 0; e < NE; ++e)
        if (!used[e] && b[e] > bv) { bv = b[e]; best = e; }
      used[best] = true;
      out[best] = p[best];  // ROUTE_SCALE = 1.0
      int pos = atomicAdd(&counts[best], 1);
      lists[best * TT + pos] = t;
    }
    for (int e = 0; e < NE; ++e) cw[(size_t)t * NE + e] = out[e];
  }
}

__global__ void k_offsets(const int* __restrict__ counts, int* __restrict__ offs) {
  if (threadIdx.x == 0) {
    int a = 0;
    for (int e = 0; e < NE; ++e) { offs[e] = a; a += counts[e]; }
    offs[NE] = a;
  }
}

// ---------------- GEMM1: SwiGLU (x@W1^T, x@W3^T) ----------------
// A [count, 2048] gathered bf16 rows of x; B^T layout W[Hdim][2048].
// tile 128x64, BK=64, 4 waves (2x2), wave tile 64x32, frag 4x2.
template <bool GATHER>
__global__ __launch_bounds__(256, 2) void k_gemm1(
    const __bf16* __restrict__ xb,
    const __bf16* __restrict__ W1, const float* __restrict__ B1,
    const __bf16* __restrict__ W3, const float* __restrict__ B3,
    __bf16* __restrict__ Hout, int Hdim,
    const int* __restrict__ counts, const int* __restrict__ offs,
    const int* __restrict__ lists) {
  int e = blockIdx.z;
  int count = GATHER ? counts[e] : TT;
  int m0 = blockIdx.y * 128;
  if (m0 >= count) return;
  int n0 = blockIdx.x * 64;
  const __bf16* W1e = W1 + (size_t)e * Hdim * DD;
  const __bf16* W3e = W3 + (size_t)e * Hdim * DD;
  const float* B1e = B1 + (size_t)e * Hdim;
  const float* B3e = B3 + (size_t)e * Hdim;
  int hbase = GATHER ? offs[e] : 0;
  const int* liste = GATHER ? lists + (size_t)e * TT : nullptr;

  __shared__ __bf16 At[128 * 64];
  __shared__ __bf16 B1t[64 * 64];
  __shared__ __bf16 B3t[64 * 64];
  __shared__ int rowtok[128];

  int tid = threadIdx.x, lane = tid & 63, wave = tid >> 6;
  if (tid < 128) {
    int s = m0 + tid;
    rowtok[tid] = GATHER ? liste[s < count ? s : 0] : (m0 + tid);
  }
  __syncthreads();

  int wm = wave >> 1, wn = wave & 1;
  f32x4 acc1[4][2] = {};
  f32x4 acc3[4][2] = {};
  int lr8 = lane >> 3;         // 0..7 row within 8-row chunk
  int lc8 = (lane & 7) * 8;    // col start (bf16 elems)
  int fr = lane & 15;
  int fk = (lane >> 4) * 8;

  for (int k0 = 0; k0 < DD; k0 += 64) {
    #pragma unroll
    for (int c = 0; c < 4; ++c) {
      int br = c * 32 + wave * 8;
      int tok = rowtok[br + lr8];
      gll16(xb + (size_t)tok * DD + k0 + lc8, &At[br * 64]);
    }
    #pragma unroll
    for (int c = 0; c < 2; ++c) {
      int br = c * 32 + wave * 8;
      gll16(W1e + (size_t)(n0 + br + lr8) * DD + k0 + lc8, &B1t[br * 64]);
      gll16(W3e + (size_t)(n0 + br + lr8) * DD + k0 + lc8, &B3t[br * 64]);
    }
    __syncthreads();
    #pragma unroll
    for (int kk = 0; kk < 2; ++kk) {
      bf16x8 af[4], b1f[2], b3f[2];
      #pragma unroll
      for (int m = 0; m < 4; ++m)
        af[m] = *(const bf16x8*)&At[(wm * 64 + m * 16 + fr) * 64 + kk * 32 + fk];
      #pragma unroll
      for (int n = 0; n < 2; ++n) {
        b1f[n] = *(const bf16x8*)&B1t[(wn * 32 + n * 16 + fr) * 64 + kk * 32 + fk];
        b3f[n] = *(const bf16x8*)&B3t[(wn * 32 + n * 16 + fr) * 64 + kk * 32 + fk];
      }
      #pragma unroll
      for (int m = 0; m < 4; ++m)
        #pragma unroll
        for (int n = 0; n < 2; ++n) {
          acc1[m][n] = __builtin_amdgcn_mfma_f32_16x16x32_bf16(af[m], b1f[n], acc1[m][n], 0, 0, 0);
          acc3[m][n] = __builtin_amdgcn_mfma_f32_16x16x32_bf16(af[m], b3f[n], acc3[m][n], 0, 0, 0);
        }
    }
    __syncthreads();
  }
  // epilogue: silu(h1+b1)*(h3+b3) -> bf16
  #pragma unroll
  for (int m = 0; m < 4; ++m)
    #pragma unroll
    for (int n = 0; n < 2; ++n)
      #pragma unroll
      for (int j = 0; j < 4; ++j) {
        int rl = wm * 64 + m * 16 + (lane >> 4) * 4 + j;
        int s = m0 + rl;
        if (s < count) {
          int col = n0 + wn * 32 + n * 16 + fr;
          float h1 = acc1[m][n][j] + B1e[col];
          float h3 = acc3[m][n][j] + B3e[col];
          float v = h1 / (1.f + expf(-h1)) * h3;
          Hout[(size_t)(hbase + s) * Hdim + col] = (__bf16)v;
        }
      }
}

// ---------------- GEMM2: out += scale*(h@W2^T + b2) ----------------
template <bool GATHER>
__global__ __launch_bounds__(256, 2) void k_gemm2(
    const __bf16* __restrict__ Hsrc, int Kd,
    const __bf16* __restrict__ W2, const float* __restrict__ B2,
    float* __restrict__ out, const float* __restrict__ cw,
    const int* __restrict__ counts, const int* __restrict__ offs,
    const int* __restrict__ lists) {
  int e = blockIdx.z;
  int count = GATHER ? counts[e] : TT;
  int m0 = blockIdx.y * 128;
  if (m0 >= count) return;
  int n0 = blockIdx.x * 64;
  const __bf16* Ae = Hsrc + (size_t)(GATHER ? offs[e] : 0) * Kd;
  const __bf16* W2e = W2 + (size_t)e * DD * Kd;
  const float* B2e = B2 + (size_t)(GATHER ? e * DD : 0);
  const int* liste = GATHER ? lists + (size_t)e * TT : nullptr;

  __shared__ __bf16 At[128 * 64];
  __shared__ __bf16 Bt[64 * 64];
  __shared__ int rowtok[128];

  int tid = threadIdx.x, lane = tid & 63, wave = tid >> 6;
  if (GATHER && tid < 128) {
    int s = m0 + tid;
    rowtok[tid] = liste[s < count ? s : 0];
  }
  __syncthreads();

  int wm = wave >> 1, wn = wave & 1;
  f32x4 acc[4][2] = {};
  int lr8 = lane >> 3;
  int lc8 = (lane & 7) * 8;
  int fr = lane & 15;
  int fk = (lane >> 4) * 8;

  for (int k0 = 0; k0 < Kd; k0 += 64) {
    #pragma unroll
    for (int c = 0; c < 4; ++c) {
      int br = c * 32 + wave * 8;
      int sr = m0 + br + lr8;
      if (sr >= count) sr = count - 1;
      gll16(Ae + (size_t)sr * Kd + k0 + lc8, &At[br * 64]);
    }
    #pragma unroll
    for (int c = 0; c < 2; ++c) {
      int br = c * 32 + wave * 8;
      gll16(W2e + (size_t)(n0 + br + lr8) * Kd + k0 + lc8, &Bt[br * 64]);
    }
    __syncthreads();
    #pragma unroll
    for (int kk = 0; kk < 2; ++kk) {
      bf16x8 af[4], bf[2];
      #pragma unroll
      for (int m = 0; m < 4; ++m)
        af[m] = *(const bf16x8*)&At[(wm * 64 + m * 16 + fr) * 64 + kk * 32 + fk];
      #pragma unroll
      for (int n = 0; n < 2; ++n)
        bf[n] = *(const bf16x8*)&Bt[(wn * 32 + n * 16 + fr) * 64 + kk * 32 + fk];
      #pragma unroll
      for (int m = 0; m < 4; ++m)
        #pragma unroll
        for (int n = 0; n < 2; ++n)
          acc[m][n] = __builtin_amdgcn_mfma_f32_16x16x32_bf16(af[m], bf[n], acc[m][n], 0, 0, 0);
    }
    __syncthreads();
  }
  #pragma unroll
  for (int m = 0; m < 4; ++m)
    #pragma unroll
    for (int n = 0; n < 2; ++n)
      #pragma unroll
      for (int j = 0; j < 4; ++j) {
        int rl = wm * 64 + m * 16 + (lane >> 4) * 4 + j;
        int s = m0 + rl;
        if (s < count) {
          int d = n0 + wn * 32 + n * 16 + fr;
          float v = acc[m][n][j] + B2e[d];
          if (GATHER) {
            int tok = rowtok[rl];
            v *= cw[(size_t)tok * NE + e];
            atomicAdd(&out[(size_t)tok * DD + d], v);
          } else {
            atomicAdd(&out[(size_t)s * DD + d], v);
          }
        }
      }
}

// ---------------- launch ----------------
extern "C" void kernel_launch(void* const* d_in, const int* in_sizes, int n_in,
                              void* d_out, int out_size, void* d_ws, size_t ws_size,
                              hipStream_t stream) {
  const float* x      = (const float*)d_in[0];
  const float* gate_w = (const float*)d_in[1];
  const float* gate_b = (const float*)d_in[2];
  const float* w1     = (const float*)d_in[3];
  const float* b1     = (const float*)d_in[4];
  const float* w2     = (const float*)d_in[5];
  const float* b2     = (const float*)d_in[6];
  const float* w3     = (const float*)d_in[7];
  const float* b3     = (const float*)d_in[8];
  const float* ws1    = (const float*)d_in[9];
  const float* bs1    = (const float*)d_in[10];
  const float* ws2    = (const float*)d_in[11];
  const float* bs2    = (const float*)d_in[12];
  const float* ws3    = (const float*)d_in[13];
  const float* bs3    = (const float*)d_in[14];
  float* outp = (float*)d_out;

  char* ws = (char*)d_ws;
  size_t off = 0;
  auto take = [&](size_t bytes) { char* p = ws + off; off += (bytes + 255) & ~(size_t)255; return p; };
  __bf16* xb   = (__bf16*)take((size_t)TT * DD * 2);
  __bf16* w1b  = (__bf16*)take((size_t)NE * HH * DD * 2);
  __bf16* w3b  = (__bf16*)take((size_t)NE * HH * DD * 2);
  __bf16* w2b  = (__bf16*)take((size_t)NE * DD * HH * 2);
  __bf16* ws1b = (__bf16*)take((size_t)HSH * DD * 2);
  __bf16* ws3b = (__bf16*)take((size_t)HSH * DD * 2);
  __bf16* ws2b = (__bf16*)take((size_t)DD * HSH * 2);
  __bf16* Hbuf = (__bf16*)take((size_t)TT * TOPK * HH * 2);
  __bf16* Sbuf = (__bf16*)take((size_t)TT * HSH * 2);
  float*  cw   = (float*)take((size_t)TT * NE * 4);
  int*    lists  = (int*)take((size_t)NE * TT * 4);
  int*    counts = (int*)take(64);
  int*    offs   = (int*)take(128);

  hipMemsetAsync(d_out, 0, (size_t)TT * DD * sizeof(float), stream);
  hipMemsetAsync(counts, 0, NE * sizeof(int), stream);

  k_cvt<<<2048, 256, 0, stream>>>(x, xb, (long)TT * DD / 4);
  k_cvt<<<2048, 256, 0, stream>>>(w1, w1b, (long)NE * HH * DD / 4);
  k_cvt<<<2048, 256, 0, stream>>>(w3, w3b, (long)NE * HH * DD / 4);
  k_cvt<<<2048, 256, 0, stream>>>(w2, w2b, (long)NE * DD * HH / 4);
  k_cvt<<<2048, 256, 0, stream>>>(ws1, ws1b, (long)HSH * DD / 4);
  k_cvt<<<2048, 256, 0, stream>>>(ws3, ws3b, (long)HSH * DD / 4);
  k_cvt<<<2048, 256, 0, stream>>>(ws2, ws2b, (long)DD * HSH / 4);

  k_gate<<<TT, 256, 0, stream>>>(x, gate_w, gate_b, cw, counts, lists);
  k_offsets<<<1, 64, 0, stream>>>(counts, offs);

  // routed experts
  k_gemm1<true><<<dim3(HH / 64, TT / 128, NE), 256, 0, stream>>>(
      xb, w1b, b1, w3b, b3, Hbuf, HH, counts, offs, lists);
  // shared expert (SwiGLU)
  k_gemm1<false><<<dim3(HSH / 64, TT / 128, 1), 256, 0, stream>>>(
      xb, ws1b, bs1, ws3b, bs3, Sbuf, HSH, nullptr, nullptr, nullptr);
  // routed down-proj + weighted scatter
  k_gemm2<true><<<dim3(DD / 64, TT / 128, NE), 256, 0, stream>>>(
      Hbuf, HH, w2b, b2, outp, cw, counts, offs, lists);
  // shared down-proj
  k_gemm2<false><<<dim3(DD / 64, TT / 128, 1), 256, 0, stream>>>(
      Sbuf, HSH, ws2b, bs2, outp, nullptr, nullptr, nullptr, nullptr);
}